// Round 1
// baseline (1803.675 us; speedup 1.0000x reference)
//
#include <hip/hip_runtime.h>

#define NN 50000
#define NE 800000
#define DIN 256
#define NH 3
#define HC 64
#define DD 192
#define DF 64

// ---- monotonic float<->unsigned for atomicMax-based segment max ----
__device__ __forceinline__ unsigned enc_f(float f) {
    unsigned u = __float_as_uint(f);
    return (u & 0x80000000u) ? ~u : (u | 0x80000000u);
}
__device__ __forceinline__ float dec_f(unsigned k) {
    return (k & 0x80000000u) ? __uint_as_float(k ^ 0x80000000u)
                             : __uint_as_float(~k);
}

// ---- generic fp32 GEMM: Y[n,DOUT] = (X (+X2)) @ W (+bias) ----
// block: TPB threads; tile BM rows x DOUT cols; thread: RPT rows x 4 cols
template<int K, int DOUT, int BM, int TPB, bool ADD2, bool BIAS>
__global__ __launch_bounds__(TPB)
void gemm_kernel(const float* __restrict__ X, const float* __restrict__ X2,
                 const float* __restrict__ W, const float* __restrict__ bias,
                 float* __restrict__ Y, int n) {
    constexpr int CG = DOUT / 4;     // col groups of 4
    constexpr int RG = TPB / CG;     // row groups
    constexpr int RPT = BM / RG;     // rows per thread
    constexpr int KP = K + 4;        // padded LDS row stride (bank shift)
    __shared__ float xs[BM * KP];

    const int tid = threadIdx.x;
    const int row0 = blockIdx.x * BM;

    constexpr int TOTAL4 = BM * (K / 4);
    for (int i = tid; i < TOTAL4; i += TPB) {
        int r = i / (K / 4);
        int c4 = i - r * (K / 4);
        float4 v = make_float4(0.f, 0.f, 0.f, 0.f);
        int row = row0 + r;
        if (row < n) {
            v = *(const float4*)(X + (size_t)row * K + c4 * 4);
            if (ADD2) {
                float4 u = *(const float4*)(X2 + (size_t)row * K + c4 * 4);
                v.x += u.x; v.y += u.y; v.z += u.z; v.w += u.w;
            }
        }
        *(float4*)(xs + r * KP + c4 * 4) = v;
    }
    __syncthreads();

    const int cg = tid % CG;
    const int rg = tid / CG;
    const int col = cg * 4;

    float acc[RPT][4];
#pragma unroll
    for (int r = 0; r < RPT; ++r) {
        acc[r][0] = 0.f; acc[r][1] = 0.f; acc[r][2] = 0.f; acc[r][3] = 0.f;
    }

    for (int k = 0; k < K; k += 4) {
        float wrow[4][4];
#pragma unroll
        for (int kk = 0; kk < 4; ++kk)
            *(float4*)&wrow[kk][0] = *(const float4*)(W + (size_t)(k + kk) * DOUT + col);
#pragma unroll
        for (int r = 0; r < RPT; ++r) {
            float xv[4];
            *(float4*)xv = *(const float4*)(xs + (rg * RPT + r) * KP + k);
#pragma unroll
            for (int kk = 0; kk < 4; ++kk)
#pragma unroll
                for (int c = 0; c < 4; ++c)
                    acc[r][c] = fmaf(xv[kk], wrow[kk][c], acc[r][c]);
        }
    }

#pragma unroll
    for (int r = 0; r < RPT; ++r) {
        int row = row0 + rg * RPT + r;
        if (row < n) {
            float4 o;
            o.x = acc[r][0]; o.y = acc[r][1]; o.z = acc[r][2]; o.w = acc[r][3];
            if (BIAS) {
                o.x += bias[col + 0]; o.y += bias[col + 1];
                o.z += bias[col + 2]; o.w += bias[col + 3];
            }
            *(float4*)(Y + (size_t)row * DOUT + col) = o;
        }
    }
}

// ---- per-node attention dots: a_s[n,h] = sum_c x[n,h,c]*att_s[h,c] ----
__global__ __launch_bounds__(192)
void attn_dots(const float* __restrict__ xf,
               const float* __restrict__ att_s, const float* __restrict__ att_d,
               float* __restrict__ as_, float* __restrict__ ad_) {
    int nidx = blockIdx.x;
    int h = threadIdx.x >> 6;
    int lane = threadIdx.x & 63;
    float v = xf[(size_t)nidx * DD + h * HC + lane];
    float s = v * att_s[h * HC + lane];
    float d = v * att_d[h * HC + lane];
#pragma unroll
    for (int off = 32; off; off >>= 1) {
        s += __shfl_down(s, off);
        d += __shfl_down(d, off);
    }
    if (lane == 0) {
        as_[nidx * NH + h] = s;
        ad_[nidx * NH + h] = d;
    }
}

// ---- edge logits + segment max (encoded atomicMax) ----
__global__ void edge_logits(const float* __restrict__ as_, const float* __restrict__ ad_,
                            const int* __restrict__ src, const int* __restrict__ dst,
                            float* __restrict__ ebuf, unsigned* __restrict__ mkeys, int ne) {
    int e = blockIdx.x * blockDim.x + threadIdx.x;
    if (e >= ne) return;
    int s = src[e], d = dst[e];
#pragma unroll
    for (int h = 0; h < NH; ++h) {
        float el = as_[s * NH + h] + ad_[d * NH + h];
        el = el > 0.f ? el : 0.2f * el;   // leaky_relu 0.2
        ebuf[(size_t)e * NH + h] = el;
        atomicMax(&mkeys[d * NH + h], enc_f(el));
    }
}

// ---- decode max keys -> float m (key==0 means no edges -> m=0) ----
__global__ void decode_max(unsigned* __restrict__ mk, int n) {
    int i = blockIdx.x * blockDim.x + threadIdx.x;
    if (i >= n) return;
    unsigned k = mk[i];
    ((float*)mk)[i] = k ? dec_f(k) : 0.f;
}

// ---- w = exp(e - m[dst]); den += w ----
__global__ void edge_weights(float* __restrict__ ebuf, const float* __restrict__ m,
                             float* __restrict__ den, const int* __restrict__ dst, int ne) {
    int e = blockIdx.x * blockDim.x + threadIdx.x;
    if (e >= ne) return;
    int d = dst[e];
#pragma unroll
    for (int h = 0; h < NH; ++h) {
        float wv = expf(ebuf[(size_t)e * NH + h] - m[d * NH + h]);
        ebuf[(size_t)e * NH + h] = wv;
        atomicAdd(&den[d * NH + h], wv);
    }
}

// ---- alpha-weighted scatter-add of source features; one wave per edge ----
__global__ __launch_bounds__(256)
void edge_aggregate(const float* __restrict__ xf, const float* __restrict__ w,
                    const float* __restrict__ den,
                    const int* __restrict__ src, const int* __restrict__ dst,
                    float* __restrict__ outp, int ne) {
    int e = blockIdx.x * 4 + (threadIdx.x >> 6);
    if (e >= ne) return;
    int lane = threadIdx.x & 63;
    int s = src[e], d = dst[e];
    float alpha[NH];
#pragma unroll
    for (int h = 0; h < NH; ++h)
        alpha[h] = w[(size_t)e * NH + h] / (den[d * NH + h] + 1e-16f);
#pragma unroll
    for (int h = 0; h < NH; ++h) {
        float v = xf[(size_t)s * DD + h * HC + lane] * alpha[h];
        atomicAdd(&outp[(size_t)d * DD + h * HC + lane], v);
    }
}

// ---- BN pass 1: per-feature sum / sumsq of relu(h + bias) ----
__global__ __launch_bounds__(192)
void bn_stats(const float* __restrict__ hbuf, const float* __restrict__ bias,
              float* __restrict__ s1, float* __restrict__ s2, int n) {
    int j = threadIdx.x;
    float b = bias[j];
    int r0 = blockIdx.x * 128;
    int r1 = min(r0 + 128, n);
    float a = 0.f, q = 0.f;
    for (int r = r0; r < r1; ++r) {
        float v = hbuf[(size_t)r * DD + j] + b;
        v = fmaxf(v, 0.f);
        a += v; q += v * v;
    }
    atomicAdd(&s1[j], a);
    atomicAdd(&s2[j], q);
}

// ---- BN pass 2: fold into scale/shift ----
__global__ void bn_finalize(const float* __restrict__ s1, const float* __restrict__ s2,
                            const float* __restrict__ g, const float* __restrict__ beta,
                            float* __restrict__ scale, float* __restrict__ shift, float invn) {
    int j = threadIdx.x;
    float mu = s1[j] * invn;
    float var = s2[j] * invn - mu * mu;
    float sc = g[j] * rsqrtf(var + 1e-5f);
    scale[j] = sc;
    shift[j] = beta[j] - mu * sc;
}

// ---- BN apply: out = relu(in + bias)*scale + shift ----
__global__ __launch_bounds__(256)
void bn_apply(const float* __restrict__ in, const float* __restrict__ bias,
              const float* __restrict__ scale, const float* __restrict__ shift,
              float* __restrict__ outp, int total) {
    int i = blockIdx.x * blockDim.x + threadIdx.x;
    if (i >= total) return;
    int j = i % DD;
    float v = fmaxf(in[i] + bias[j], 0.f);
    outp[i] = v * scale[j] + shift[j];
}

extern "C" void kernel_launch(void* const* d_in, const int* in_sizes, int n_in,
                              void* d_out, int out_size, void* d_ws, size_t ws_size,
                              hipStream_t stream) {
    const float* x   = (const float*)d_in[0];
    const float* W1  = (const float*)d_in[1];
    const float* as1 = (const float*)d_in[2];
    const float* ad1 = (const float*)d_in[3];
    const float* b1  = (const float*)d_in[4];
    const float* g1  = (const float*)d_in[5];
    const float* be1 = (const float*)d_in[6];
    const float* W2  = (const float*)d_in[7];
    const float* as2 = (const float*)d_in[8];
    const float* ad2 = (const float*)d_in[9];
    const float* b2  = (const float*)d_in[10];
    const float* g2  = (const float*)d_in[11];
    const float* be2 = (const float*)d_in[12];
    const float* Wf  = (const float*)d_in[13];
    const float* bf  = (const float*)d_in[14];
    const int*   ei  = (const int*)d_in[15];
    const int* src = ei;
    const int* dst = ei + NE;
    float* out = (float*)d_out;

    float* ws = (float*)d_ws;
    float* A   = ws;                          // [N,192] layer features
    float* H1  = A   + (size_t)NN * DD;       // [N,192] h1 (post-BN)
    float* CB  = H1  + (size_t)NN * DD;       // [N,192] aggregate / h2
    float* EW  = CB  + (size_t)NN * DD;       // [E,3] logits -> weights
    float* AS  = EW  + (size_t)NE * NH;       // [N,3]
    float* AD  = AS  + (size_t)NN * NH;       // [N,3]
    float* MK  = AD  + (size_t)NN * NH;       // [N,3] max keys -> m
    float* DEN = MK  + (size_t)NN * NH;       // [N,3]
    float* S1  = DEN + (size_t)NN * NH;       // [192]
    float* S2  = S1 + DD;                     // [192]
    float* SC  = S2 + DD;                     // [192]
    float* SH  = SC + DD;                     // [192]

    const int gemm1_grid = (NN + 31) / 32;
    const int edge_grid  = (NE + 255) / 256;
    const int dec_grid   = (NN * NH + 255) / 256;
    const int agg_grid   = (NE + 3) / 4;
    const int bns_grid   = (NN + 127) / 128;
    const int bna_grid   = (NN * DD + 255) / 256;

    // ================= layer 1 =================
    gemm_kernel<DIN, DD, 32, 192, false, false>
        <<<gemm1_grid, 192, 0, stream>>>(x, nullptr, W1, nullptr, A, NN);
    attn_dots<<<NN, 192, 0, stream>>>(A, as1, ad1, AS, AD);
    hipMemsetAsync(MK, 0, (size_t)NN * NH * 4, stream);
    hipMemsetAsync(DEN, 0, (size_t)NN * NH * 4, stream);
    hipMemsetAsync(CB, 0, (size_t)NN * DD * 4, stream);
    hipMemsetAsync(S1, 0, 2 * DD * 4, stream);
    edge_logits<<<edge_grid, 256, 0, stream>>>(AS, AD, src, dst, EW, (unsigned*)MK, NE);
    decode_max<<<dec_grid, 256, 0, stream>>>((unsigned*)MK, NN * NH);
    edge_weights<<<edge_grid, 256, 0, stream>>>(EW, MK, DEN, dst, NE);
    edge_aggregate<<<agg_grid, 256, 0, stream>>>(A, EW, DEN, src, dst, CB, NE);
    bn_stats<<<bns_grid, 192, 0, stream>>>(CB, b1, S1, S2, NN);
    bn_finalize<<<1, DD, 0, stream>>>(S1, S2, g1, be1, SC, SH, 1.0f / NN);
    bn_apply<<<bna_grid, 256, 0, stream>>>(CB, b1, SC, SH, H1, NN * DD);

    // ================= layer 2 =================
    gemm_kernel<DD, DD, 32, 192, false, false>
        <<<gemm1_grid, 192, 0, stream>>>(H1, nullptr, W2, nullptr, A, NN);
    attn_dots<<<NN, 192, 0, stream>>>(A, as2, ad2, AS, AD);
    hipMemsetAsync(MK, 0, (size_t)NN * NH * 4, stream);
    hipMemsetAsync(DEN, 0, (size_t)NN * NH * 4, stream);
    hipMemsetAsync(CB, 0, (size_t)NN * DD * 4, stream);
    hipMemsetAsync(S1, 0, 2 * DD * 4, stream);
    edge_logits<<<edge_grid, 256, 0, stream>>>(AS, AD, src, dst, EW, (unsigned*)MK, NE);
    decode_max<<<dec_grid, 256, 0, stream>>>((unsigned*)MK, NN * NH);
    edge_weights<<<edge_grid, 256, 0, stream>>>(EW, MK, DEN, dst, NE);
    edge_aggregate<<<agg_grid, 256, 0, stream>>>(A, EW, DEN, src, dst, CB, NE);
    bn_stats<<<bns_grid, 192, 0, stream>>>(CB, b2, S1, S2, NN);
    bn_finalize<<<1, DD, 0, stream>>>(S1, S2, g2, be2, SC, SH, 1.0f / NN);
    bn_apply<<<bna_grid, 256, 0, stream>>>(CB, b2, SC, SH, CB, NN * DD);

    // ================= final: out = (h1 + h2) @ Wf + bf =================
    gemm_kernel<DD, DF, 64, 128, true, true>
        <<<(NN + 63) / 64, 128, 0, stream>>>(H1, CB, Wf, bf, out, NN);
}

// Round 2
// 780.574 us; speedup vs baseline: 2.3107x; 2.3107x over previous
//
#include <hip/hip_runtime.h>

#define NN 50000
#define NE 800000
#define DIN 256
#define NH 3
#define HC 64
#define DD 192
#define DF 64

// ---- generic fp32 GEMM: Y[n,DOUT] = (X (+X2)) @ W (+bias) ----
template<int K, int DOUT, int BM, int TPB, bool ADD2, bool BIAS>
__global__ __launch_bounds__(TPB)
void gemm_kernel(const float* __restrict__ X, const float* __restrict__ X2,
                 const float* __restrict__ W, const float* __restrict__ bias,
                 float* __restrict__ Y, int n) {
    constexpr int CG = DOUT / 4;     // col groups of 4
    constexpr int RG = TPB / CG;     // row groups
    constexpr int RPT = BM / RG;     // rows per thread
    constexpr int KP = K + 4;        // padded LDS row stride
    __shared__ float xs[BM * KP];

    const int tid = threadIdx.x;
    const int row0 = blockIdx.x * BM;

    constexpr int TOTAL4 = BM * (K / 4);
    for (int i = tid; i < TOTAL4; i += TPB) {
        int r = i / (K / 4);
        int c4 = i - r * (K / 4);
        float4 v = make_float4(0.f, 0.f, 0.f, 0.f);
        int row = row0 + r;
        if (row < n) {
            v = *(const float4*)(X + (size_t)row * K + c4 * 4);
            if (ADD2) {
                float4 u = *(const float4*)(X2 + (size_t)row * K + c4 * 4);
                v.x += u.x; v.y += u.y; v.z += u.z; v.w += u.w;
            }
        }
        *(float4*)(xs + r * KP + c4 * 4) = v;
    }
    __syncthreads();

    const int cg = tid % CG;
    const int rg = tid / CG;
    const int col = cg * 4;

    float acc[RPT][4];
#pragma unroll
    for (int r = 0; r < RPT; ++r) {
        acc[r][0] = 0.f; acc[r][1] = 0.f; acc[r][2] = 0.f; acc[r][3] = 0.f;
    }

    for (int k = 0; k < K; k += 4) {
        float wrow[4][4];
#pragma unroll
        for (int kk = 0; kk < 4; ++kk)
            *(float4*)&wrow[kk][0] = *(const float4*)(W + (size_t)(k + kk) * DOUT + col);
#pragma unroll
        for (int r = 0; r < RPT; ++r) {
            float xv[4];
            *(float4*)xv = *(const float4*)(xs + (rg * RPT + r) * KP + k);
#pragma unroll
            for (int kk = 0; kk < 4; ++kk)
#pragma unroll
                for (int c = 0; c < 4; ++c)
                    acc[r][c] = fmaf(xv[kk], wrow[kk][c], acc[r][c]);
        }
    }

#pragma unroll
    for (int r = 0; r < RPT; ++r) {
        int row = row0 + rg * RPT + r;
        if (row < n) {
            float4 o;
            o.x = acc[r][0]; o.y = acc[r][1]; o.z = acc[r][2]; o.w = acc[r][3];
            if (BIAS) {
                o.x += bias[col + 0]; o.y += bias[col + 1];
                o.z += bias[col + 2]; o.w += bias[col + 3];
            }
            *(float4*)(Y + (size_t)row * DOUT + col) = o;
        }
    }
}

// ---- per-node attention dots ----
__global__ __launch_bounds__(192)
void attn_dots(const float* __restrict__ xf,
               const float* __restrict__ att_s, const float* __restrict__ att_d,
               float* __restrict__ as_, float* __restrict__ ad_) {
    int nidx = blockIdx.x;
    int h = threadIdx.x >> 6;
    int lane = threadIdx.x & 63;
    float v = xf[(size_t)nidx * DD + h * HC + lane];
    float s = v * att_s[h * HC + lane];
    float d = v * att_d[h * HC + lane];
#pragma unroll
    for (int off = 32; off; off >>= 1) {
        s += __shfl_down(s, off);
        d += __shfl_down(d, off);
    }
    if (lane == 0) {
        as_[nidx * NH + h] = s;
        ad_[nidx * NH + h] = d;
    }
}

// ============ CSR build (edge list shared by both layers) ============
__global__ void hist_kernel(const int* __restrict__ dst, int* __restrict__ deg, int ne) {
    int e = blockIdx.x * blockDim.x + threadIdx.x;
    if (e < ne) atomicAdd(&deg[dst[e]], 1);
}

__global__ __launch_bounds__(1024)
void scan_kernel(const int* __restrict__ deg, int* __restrict__ rowptr,
                 int* __restrict__ cursor) {
    __shared__ int part[1024];
    const int t = threadIdx.x;
    const int CH = (NN + 1023) / 1024;   // 49
    const int b = t * CH;
    int sum = 0;
    for (int i = 0; i < CH; ++i) {
        int idx = b + i;
        if (idx < NN) sum += deg[idx];
    }
    part[t] = sum;
    __syncthreads();
    for (int off = 1; off < 1024; off <<= 1) {
        int u = (t >= off) ? part[t - off] : 0;
        int v = part[t];
        __syncthreads();
        part[t] = u + v;
        __syncthreads();
    }
    int run = (t == 0) ? 0 : part[t - 1];
    for (int i = 0; i < CH; ++i) {
        int idx = b + i;
        if (idx < NN) {
            rowptr[idx] = run;
            cursor[idx] = run;
            run += deg[idx];
        }
    }
    if (t == 1023) rowptr[NN] = part[1023];
}

__global__ void scatter_kernel(const int* __restrict__ src, const int* __restrict__ dst,
                               int* __restrict__ cursor, int* __restrict__ csr_src, int ne) {
    int e = blockIdx.x * blockDim.x + threadIdx.x;
    if (e >= ne) return;
    int d = dst[e];
    int pos = atomicAdd(&cursor[d], 1);
    csr_src[pos] = src[e];
}

// ============ fused per-destination GAT: logits+softmax+aggregate ============
// one wave per dst node; lane owns channels {lane, lane+64, lane+128}
__global__ __launch_bounds__(256)
void gat_gather(const float* __restrict__ xf,
                const float* __restrict__ as_, const float* __restrict__ ad_,
                const int* __restrict__ rowptr, const int* __restrict__ csr_src,
                float* __restrict__ outp) {
    int d = blockIdx.x * 4 + (threadIdx.x >> 6);
    if (d >= NN) return;
    int lane = threadIdx.x & 63;
    int beg = rowptr[d], end = rowptr[d + 1];
    float ad0 = ad_[d * NH + 0], ad1 = ad_[d * NH + 1], ad2 = ad_[d * NH + 2];

    // pass 1: per-head max over incoming edges (lanes parallel over edges)
    float m0 = -1e30f, m1 = -1e30f, m2 = -1e30f;
    for (int i = beg + lane; i < end; i += 64) {
        int s = csr_src[i];
        float e0 = as_[s * NH + 0] + ad0;
        float e1 = as_[s * NH + 1] + ad1;
        float e2 = as_[s * NH + 2] + ad2;
        e0 = e0 > 0.f ? e0 : 0.2f * e0;
        e1 = e1 > 0.f ? e1 : 0.2f * e1;
        e2 = e2 > 0.f ? e2 : 0.2f * e2;
        m0 = fmaxf(m0, e0); m1 = fmaxf(m1, e1); m2 = fmaxf(m2, e2);
    }
#pragma unroll
    for (int off = 1; off < 64; off <<= 1) {
        m0 = fmaxf(m0, __shfl_xor(m0, off));
        m1 = fmaxf(m1, __shfl_xor(m1, off));
        m2 = fmaxf(m2, __shfl_xor(m2, off));
    }

    // pass 2: whole wave walks each edge; accumulate w*x and den in regs
    float a0 = 0.f, a1 = 0.f, a2 = 0.f;
    float den0 = 0.f, den1 = 0.f, den2 = 0.f;
    for (int i = beg; i < end; ++i) {
        int s = csr_src[i];
        s = __builtin_amdgcn_readfirstlane(s);
        float e0 = as_[s * NH + 0] + ad0;
        float e1 = as_[s * NH + 1] + ad1;
        float e2 = as_[s * NH + 2] + ad2;
        e0 = e0 > 0.f ? e0 : 0.2f * e0;
        e1 = e1 > 0.f ? e1 : 0.2f * e1;
        e2 = e2 > 0.f ? e2 : 0.2f * e2;
        float w0 = __expf(e0 - m0);
        float w1 = __expf(e1 - m1);
        float w2 = __expf(e2 - m2);
        den0 += w0; den1 += w1; den2 += w2;
        const float* xs = xf + (size_t)s * DD;
        a0 = fmaf(xs[lane],       w0, a0);
        a1 = fmaf(xs[64 + lane],  w1, a1);
        a2 = fmaf(xs[128 + lane], w2, a2);
    }
    size_t o = (size_t)d * DD + lane;
    outp[o]       = a0 / (den0 + 1e-16f);
    outp[o + 64]  = a1 / (den1 + 1e-16f);
    outp[o + 128] = a2 / (den2 + 1e-16f);
}

// ---- BN pass 1: per-feature sum / sumsq of relu(h + bias) ----
__global__ __launch_bounds__(192)
void bn_stats(const float* __restrict__ hbuf, const float* __restrict__ bias,
              float* __restrict__ s1, float* __restrict__ s2, int n) {
    int j = threadIdx.x;
    float b = bias[j];
    int r0 = blockIdx.x * 128;
    int r1 = min(r0 + 128, n);
    float a = 0.f, q = 0.f;
    for (int r = r0; r < r1; ++r) {
        float v = hbuf[(size_t)r * DD + j] + b;
        v = fmaxf(v, 0.f);
        a += v; q += v * v;
    }
    atomicAdd(&s1[j], a);
    atomicAdd(&s2[j], q);
}

__global__ void bn_finalize(const float* __restrict__ s1, const float* __restrict__ s2,
                            const float* __restrict__ g, const float* __restrict__ beta,
                            float* __restrict__ scale, float* __restrict__ shift, float invn) {
    int j = threadIdx.x;
    float mu = s1[j] * invn;
    float var = s2[j] * invn - mu * mu;
    float sc = g[j] * rsqrtf(var + 1e-5f);
    scale[j] = sc;
    shift[j] = beta[j] - mu * sc;
}

__global__ __launch_bounds__(256)
void bn_apply(const float* __restrict__ in, const float* __restrict__ bias,
              const float* __restrict__ scale, const float* __restrict__ shift,
              float* __restrict__ outp, int total) {
    int i = blockIdx.x * blockDim.x + threadIdx.x;
    if (i >= total) return;
    int j = i % DD;
    float v = fmaxf(in[i] + bias[j], 0.f);
    outp[i] = v * scale[j] + shift[j];
}

extern "C" void kernel_launch(void* const* d_in, const int* in_sizes, int n_in,
                              void* d_out, int out_size, void* d_ws, size_t ws_size,
                              hipStream_t stream) {
    const float* x   = (const float*)d_in[0];
    const float* W1  = (const float*)d_in[1];
    const float* as1 = (const float*)d_in[2];
    const float* ad1 = (const float*)d_in[3];
    const float* b1  = (const float*)d_in[4];
    const float* g1  = (const float*)d_in[5];
    const float* be1 = (const float*)d_in[6];
    const float* W2  = (const float*)d_in[7];
    const float* as2 = (const float*)d_in[8];
    const float* ad2 = (const float*)d_in[9];
    const float* b2  = (const float*)d_in[10];
    const float* g2  = (const float*)d_in[11];
    const float* be2 = (const float*)d_in[12];
    const float* Wf  = (const float*)d_in[13];
    const float* bf  = (const float*)d_in[14];
    const int*   ei  = (const int*)d_in[15];
    const int* src = ei;
    const int* dst = ei + NE;
    float* out = (float*)d_out;

    float* ws = (float*)d_ws;
    float* A   = ws;                          // [N,192] layer features
    float* H1  = A   + (size_t)NN * DD;       // [N,192] h1 (post-BN)
    float* CB  = H1  + (size_t)NN * DD;       // [N,192] aggregate / h2
    float* AS  = CB  + (size_t)NN * DD;       // [N,3]
    float* AD  = AS  + (size_t)NN * NH;       // [N,3]
    float* S1  = AD  + (size_t)NN * NH;       // [192]
    float* S2  = S1 + DD;
    float* SC  = S2 + DD;
    float* SH  = SC + DD;
    int* DEG    = (int*)(SH + DD);            // [N]
    int* ROWPTR = DEG + NN;                   // [N+1]
    int* CURSOR = ROWPTR + NN + 1;            // [N]
    int* CSRS   = CURSOR + NN;                // [E] src sorted by dst

    const int gemm1_grid = (NN + 31) / 32;
    const int edge_grid  = (NE + 255) / 256;
    const int gat_grid   = (NN + 3) / 4;
    const int bns_grid   = (NN + 127) / 128;
    const int bna_grid   = (NN * DD + 255) / 256;

    // ---- CSR build (once; shared by both layers) ----
    hipMemsetAsync(DEG, 0, (size_t)NN * 4, stream);
    hist_kernel<<<edge_grid, 256, 0, stream>>>(dst, DEG, NE);
    scan_kernel<<<1, 1024, 0, stream>>>(DEG, ROWPTR, CURSOR);
    scatter_kernel<<<edge_grid, 256, 0, stream>>>(src, dst, CURSOR, CSRS, NE);

    // ================= layer 1 =================
    gemm_kernel<DIN, DD, 32, 192, false, false>
        <<<gemm1_grid, 192, 0, stream>>>(x, nullptr, W1, nullptr, A, NN);
    attn_dots<<<NN, 192, 0, stream>>>(A, as1, ad1, AS, AD);
    gat_gather<<<gat_grid, 256, 0, stream>>>(A, AS, AD, ROWPTR, CSRS, CB);
    hipMemsetAsync(S1, 0, 2 * DD * 4, stream);
    bn_stats<<<bns_grid, 192, 0, stream>>>(CB, b1, S1, S2, NN);
    bn_finalize<<<1, DD, 0, stream>>>(S1, S2, g1, be1, SC, SH, 1.0f / NN);
    bn_apply<<<bna_grid, 256, 0, stream>>>(CB, b1, SC, SH, H1, NN * DD);

    // ================= layer 2 =================
    gemm_kernel<DD, DD, 32, 192, false, false>
        <<<gemm1_grid, 192, 0, stream>>>(H1, nullptr, W2, nullptr, A, NN);
    attn_dots<<<NN, 192, 0, stream>>>(A, as2, ad2, AS, AD);
    gat_gather<<<gat_grid, 256, 0, stream>>>(A, AS, AD, ROWPTR, CSRS, CB);
    hipMemsetAsync(S1, 0, 2 * DD * 4, stream);
    bn_stats<<<bns_grid, 192, 0, stream>>>(CB, b2, S1, S2, NN);
    bn_finalize<<<1, DD, 0, stream>>>(S1, S2, g2, be2, SC, SH, 1.0f / NN);
    bn_apply<<<bna_grid, 256, 0, stream>>>(CB, b2, SC, SH, CB, NN * DD);

    // ================= final: out = (h1 + h2) @ Wf + bf =================
    gemm_kernel<DD, DF, 64, 128, true, true>
        <<<(NN + 63) / 64, 128, 0, stream>>>(H1, CB, Wf, bf, out, NN);
}

// Round 3
// 669.738 us; speedup vs baseline: 2.6931x; 1.1655x over previous
//
#include <hip/hip_runtime.h>

#define NN 50000
#define NE 800000
#define DIN 256
#define NH 3
#define HC 64
#define DD 192
#define DF 64
#define NB 196   // (NN + 255) / 256

// ---- generic fp32 GEMM: Y[n,DOUT] = (X (+X2)) @ W (+bias) ----
template<int K, int DOUT, int BM, int TPB, bool ADD2, bool BIAS>
__global__ __launch_bounds__(TPB)
void gemm_kernel(const float* __restrict__ X, const float* __restrict__ X2,
                 const float* __restrict__ W, const float* __restrict__ bias,
                 float* __restrict__ Y, int n) {
    constexpr int CG = DOUT / 4;     // col groups of 4
    constexpr int RG = TPB / CG;     // row groups
    constexpr int RPT = BM / RG;     // rows per thread
    constexpr int KP = K + 4;        // padded LDS row stride
    __shared__ float xs[BM * KP];

    const int tid = threadIdx.x;
    const int row0 = blockIdx.x * BM;

    constexpr int TOTAL4 = BM * (K / 4);
    for (int i = tid; i < TOTAL4; i += TPB) {
        int r = i / (K / 4);
        int c4 = i - r * (K / 4);
        float4 v = make_float4(0.f, 0.f, 0.f, 0.f);
        int row = row0 + r;
        if (row < n) {
            v = *(const float4*)(X + (size_t)row * K + c4 * 4);
            if (ADD2) {
                float4 u = *(const float4*)(X2 + (size_t)row * K + c4 * 4);
                v.x += u.x; v.y += u.y; v.z += u.z; v.w += u.w;
            }
        }
        *(float4*)(xs + r * KP + c4 * 4) = v;
    }
    __syncthreads();

    const int cg = tid % CG;
    const int rg = tid / CG;
    const int col = cg * 4;

    float acc[RPT][4];
#pragma unroll
    for (int r = 0; r < RPT; ++r) {
        acc[r][0] = 0.f; acc[r][1] = 0.f; acc[r][2] = 0.f; acc[r][3] = 0.f;
    }

    for (int k = 0; k < K; k += 4) {
        float wrow[4][4];
#pragma unroll
        for (int kk = 0; kk < 4; ++kk)
            *(float4*)&wrow[kk][0] = *(const float4*)(W + (size_t)(k + kk) * DOUT + col);
#pragma unroll
        for (int r = 0; r < RPT; ++r) {
            float xv[4];
            *(float4*)xv = *(const float4*)(xs + (rg * RPT + r) * KP + k);
#pragma unroll
            for (int kk = 0; kk < 4; ++kk)
#pragma unroll
                for (int c = 0; c < 4; ++c)
                    acc[r][c] = fmaf(xv[kk], wrow[kk][c], acc[r][c]);
        }
    }

#pragma unroll
    for (int r = 0; r < RPT; ++r) {
        int row = row0 + rg * RPT + r;
        if (row < n) {
            float4 o;
            o.x = acc[r][0]; o.y = acc[r][1]; o.z = acc[r][2]; o.w = acc[r][3];
            if (BIAS) {
                o.x += bias[col + 0]; o.y += bias[col + 1];
                o.z += bias[col + 2]; o.w += bias[col + 3];
            }
            *(float4*)(Y + (size_t)row * DOUT + col) = o;
        }
    }
}

// ---- per-node attention dots ----
__global__ __launch_bounds__(192)
void attn_dots(const float* __restrict__ xf,
               const float* __restrict__ att_s, const float* __restrict__ att_d,
               float* __restrict__ as_, float* __restrict__ ad_) {
    int nidx = blockIdx.x;
    int h = threadIdx.x >> 6;
    int lane = threadIdx.x & 63;
    float v = xf[(size_t)nidx * DD + h * HC + lane];
    float s = v * att_s[h * HC + lane];
    float d = v * att_d[h * HC + lane];
#pragma unroll
    for (int off = 32; off; off >>= 1) {
        s += __shfl_down(s, off);
        d += __shfl_down(d, off);
    }
    if (lane == 0) {
        as_[nidx * NH + h] = s;
        ad_[nidx * NH + h] = d;
    }
}

// ============ CSR build (edge list shared by both layers) ============
__global__ void hist_kernel(const int* __restrict__ dst, int* __restrict__ deg, int ne) {
    int e = blockIdx.x * blockDim.x + threadIdx.x;
    if (e < ne) atomicAdd(&deg[dst[e]], 1);
}

// stage 1: per-block (256 elems) sums
__global__ __launch_bounds__(256)
void blocksum_kernel(const int* __restrict__ deg, int* __restrict__ bsum) {
    int i = blockIdx.x * 256 + threadIdx.x;
    int v = (i < NN) ? deg[i] : 0;
#pragma unroll
    for (int off = 32; off; off >>= 1) v += __shfl_down(v, off);
    __shared__ int ws[4];
    if ((threadIdx.x & 63) == 0) ws[threadIdx.x >> 6] = v;
    __syncthreads();
    if (threadIdx.x == 0) bsum[blockIdx.x] = ws[0] + ws[1] + ws[2] + ws[3];
}

// stage 2: scan the NB block sums (one block)
__global__ __launch_bounds__(256)
void scan_bsums(const int* __restrict__ bsum, int* __restrict__ boff,
                int* __restrict__ rowptr) {
    __shared__ int s[256];
    int t = threadIdx.x;
    int v = (t < NB) ? bsum[t] : 0;
    s[t] = v;
    __syncthreads();
    for (int off = 1; off < 256; off <<= 1) {
        int u = (t >= off) ? s[t - off] : 0;
        __syncthreads();
        s[t] += u;
        __syncthreads();
    }
    if (t < NB) boff[t] = s[t] - v;          // exclusive
    if (t == 255) rowptr[NN] = s[255];       // total
}

// stage 3: per-block local scan + offset -> rowptr, cursor
__global__ __launch_bounds__(256)
void expand_kernel(const int* __restrict__ deg, const int* __restrict__ boff,
                   int* __restrict__ rowptr, int* __restrict__ cursor) {
    __shared__ int s[256];
    int t = threadIdx.x;
    int i = blockIdx.x * 256 + t;
    int v = (i < NN) ? deg[i] : 0;
    s[t] = v;
    __syncthreads();
    for (int off = 1; off < 256; off <<= 1) {
        int u = (t >= off) ? s[t - off] : 0;
        __syncthreads();
        s[t] += u;
        __syncthreads();
    }
    if (i < NN) {
        int excl = s[t] - v + boff[blockIdx.x];
        rowptr[i] = excl;
        cursor[i] = excl;
    }
}

__global__ void scatter_kernel(const int* __restrict__ src, const int* __restrict__ dst,
                               int* __restrict__ cursor, int* __restrict__ csr_src, int ne) {
    int e = blockIdx.x * blockDim.x + threadIdx.x;
    if (e >= ne) return;
    int d = dst[e];
    int pos = atomicAdd(&cursor[d], 1);
    csr_src[pos] = src[e];
}

// ============ fused per-destination GAT: logits+softmax+aggregate ============
__global__ __launch_bounds__(256)
void gat_gather(const float* __restrict__ xf,
                const float* __restrict__ as_, const float* __restrict__ ad_,
                const int* __restrict__ rowptr, const int* __restrict__ csr_src,
                float* __restrict__ outp) {
    int d = blockIdx.x * 4 + (threadIdx.x >> 6);
    if (d >= NN) return;
    int lane = threadIdx.x & 63;
    int beg = rowptr[d], end = rowptr[d + 1];
    float ad0 = ad_[d * NH + 0], ad1 = ad_[d * NH + 1], ad2 = ad_[d * NH + 2];

    // pass 1: per-head max (lanes parallel over edges)
    float m0 = -1e30f, m1 = -1e30f, m2 = -1e30f;
    for (int i = beg + lane; i < end; i += 64) {
        int s = csr_src[i];
        float e0 = as_[s * NH + 0] + ad0;
        float e1 = as_[s * NH + 1] + ad1;
        float e2 = as_[s * NH + 2] + ad2;
        e0 = e0 > 0.f ? e0 : 0.2f * e0;
        e1 = e1 > 0.f ? e1 : 0.2f * e1;
        e2 = e2 > 0.f ? e2 : 0.2f * e2;
        m0 = fmaxf(m0, e0); m1 = fmaxf(m1, e1); m2 = fmaxf(m2, e2);
    }
#pragma unroll
    for (int off = 1; off < 64; off <<= 1) {
        m0 = fmaxf(m0, __shfl_xor(m0, off));
        m1 = fmaxf(m1, __shfl_xor(m1, off));
        m2 = fmaxf(m2, __shfl_xor(m2, off));
    }

    // pass 2: whole wave walks each edge; accumulate w*x and den in regs
    float a0 = 0.f, a1 = 0.f, a2 = 0.f;
    float den0 = 0.f, den1 = 0.f, den2 = 0.f;
    for (int i = beg; i < end; ++i) {
        int s = csr_src[i];
        s = __builtin_amdgcn_readfirstlane(s);
        float e0 = as_[s * NH + 0] + ad0;
        float e1 = as_[s * NH + 1] + ad1;
        float e2 = as_[s * NH + 2] + ad2;
        e0 = e0 > 0.f ? e0 : 0.2f * e0;
        e1 = e1 > 0.f ? e1 : 0.2f * e1;
        e2 = e2 > 0.f ? e2 : 0.2f * e2;
        float w0 = __expf(e0 - m0);
        float w1 = __expf(e1 - m1);
        float w2 = __expf(e2 - m2);
        den0 += w0; den1 += w1; den2 += w2;
        const float* xs = xf + (size_t)s * DD;
        a0 = fmaf(xs[lane],       w0, a0);
        a1 = fmaf(xs[64 + lane],  w1, a1);
        a2 = fmaf(xs[128 + lane], w2, a2);
    }
    size_t o = (size_t)d * DD + lane;
    outp[o]       = a0 / (den0 + 1e-16f);
    outp[o + 64]  = a1 / (den1 + 1e-16f);
    outp[o + 128] = a2 / (den2 + 1e-16f);
}

// ---- BN pass 1: per-feature sum / sumsq of relu(h + bias) ----
__global__ __launch_bounds__(192)
void bn_stats(const float* __restrict__ hbuf, const float* __restrict__ bias,
              float* __restrict__ s1, float* __restrict__ s2, int n) {
    int j = threadIdx.x;
    float b = bias[j];
    int r0 = blockIdx.x * 128;
    int r1 = min(r0 + 128, n);
    float a = 0.f, q = 0.f;
    for (int r = r0; r < r1; ++r) {
        float v = hbuf[(size_t)r * DD + j] + b;
        v = fmaxf(v, 0.f);
        a += v; q += v * v;
    }
    atomicAdd(&s1[j], a);
    atomicAdd(&s2[j], q);
}

__global__ void bn_finalize(const float* __restrict__ s1, const float* __restrict__ s2,
                            const float* __restrict__ g, const float* __restrict__ beta,
                            float* __restrict__ scale, float* __restrict__ shift, float invn) {
    int j = threadIdx.x;
    float mu = s1[j] * invn;
    float var = s2[j] * invn - mu * mu;
    float sc = g[j] * rsqrtf(var + 1e-5f);
    scale[j] = sc;
    shift[j] = beta[j] - mu * sc;
}

__global__ __launch_bounds__(256)
void bn_apply(const float* __restrict__ in, const float* __restrict__ bias,
              const float* __restrict__ scale, const float* __restrict__ shift,
              float* __restrict__ outp, int total) {
    int i = blockIdx.x * blockDim.x + threadIdx.x;
    if (i >= total) return;
    int j = i % DD;
    float v = fmaxf(in[i] + bias[j], 0.f);
    outp[i] = v * scale[j] + shift[j];
}

extern "C" void kernel_launch(void* const* d_in, const int* in_sizes, int n_in,
                              void* d_out, int out_size, void* d_ws, size_t ws_size,
                              hipStream_t stream) {
    const float* x   = (const float*)d_in[0];
    const float* W1  = (const float*)d_in[1];
    const float* as1 = (const float*)d_in[2];
    const float* ad1 = (const float*)d_in[3];
    const float* b1  = (const float*)d_in[4];
    const float* g1  = (const float*)d_in[5];
    const float* be1 = (const float*)d_in[6];
    const float* W2  = (const float*)d_in[7];
    const float* as2 = (const float*)d_in[8];
    const float* ad2 = (const float*)d_in[9];
    const float* b2  = (const float*)d_in[10];
    const float* g2  = (const float*)d_in[11];
    const float* be2 = (const float*)d_in[12];
    const float* Wf  = (const float*)d_in[13];
    const float* bf  = (const float*)d_in[14];
    const int*   ei  = (const int*)d_in[15];
    const int* src = ei;
    const int* dst = ei + NE;
    float* out = (float*)d_out;

    float* ws = (float*)d_ws;
    float* A   = ws;                          // [N,192] layer features
    float* H1  = A   + (size_t)NN * DD;       // [N,192] h1 (post-BN)
    float* CB  = H1  + (size_t)NN * DD;       // [N,192] aggregate / h2
    float* AS  = CB  + (size_t)NN * DD;       // [N,3]
    float* AD  = AS  + (size_t)NN * NH;       // [N,3]
    float* S1  = AD  + (size_t)NN * NH;       // [192]
    float* S2  = S1 + DD;
    float* SC  = S2 + DD;
    float* SH  = SC + DD;
    int* DEG    = (int*)(SH + DD);            // [N]
    int* ROWPTR = DEG + NN;                   // [N+1]
    int* CURSOR = ROWPTR + NN + 1;            // [N]
    int* BSUM   = CURSOR + NN;                // [NB]
    int* BOFF   = BSUM + NB;                  // [NB]
    int* CSRS   = BOFF + NB;                  // [E] src sorted by dst

    const int gemm1_grid = (NN + 31) / 32;
    const int edge_grid  = (NE + 255) / 256;
    const int gat_grid   = (NN + 3) / 4;
    const int bns_grid   = (NN + 127) / 128;
    const int bna_grid   = (NN * DD + 255) / 256;

    // ---- CSR build (once; shared by both layers) ----
    hipMemsetAsync(DEG, 0, (size_t)NN * 4, stream);
    hist_kernel<<<edge_grid, 256, 0, stream>>>(dst, DEG, NE);
    blocksum_kernel<<<NB, 256, 0, stream>>>(DEG, BSUM);
    scan_bsums<<<1, 256, 0, stream>>>(BSUM, BOFF, ROWPTR);
    expand_kernel<<<NB, 256, 0, stream>>>(DEG, BOFF, ROWPTR, CURSOR);
    scatter_kernel<<<edge_grid, 256, 0, stream>>>(src, dst, CURSOR, CSRS, NE);

    // ================= layer 1 =================
    gemm_kernel<DIN, DD, 32, 192, false, false>
        <<<gemm1_grid, 192, 0, stream>>>(x, nullptr, W1, nullptr, A, NN);
    attn_dots<<<NN, 192, 0, stream>>>(A, as1, ad1, AS, AD);
    gat_gather<<<gat_grid, 256, 0, stream>>>(A, AS, AD, ROWPTR, CSRS, CB);
    hipMemsetAsync(S1, 0, 2 * DD * 4, stream);
    bn_stats<<<bns_grid, 192, 0, stream>>>(CB, b1, S1, S2, NN);
    bn_finalize<<<1, DD, 0, stream>>>(S1, S2, g1, be1, SC, SH, 1.0f / NN);
    bn_apply<<<bna_grid, 256, 0, stream>>>(CB, b1, SC, SH, H1, NN * DD);

    // ================= layer 2 =================
    gemm_kernel<DD, DD, 32, 192, false, false>
        <<<gemm1_grid, 192, 0, stream>>>(H1, nullptr, W2, nullptr, A, NN);
    attn_dots<<<NN, 192, 0, stream>>>(A, as2, ad2, AS, AD);
    gat_gather<<<gat_grid, 256, 0, stream>>>(A, AS, AD, ROWPTR, CSRS, CB);
    hipMemsetAsync(S1, 0, 2 * DD * 4, stream);
    bn_stats<<<bns_grid, 192, 0, stream>>>(CB, b2, S1, S2, NN);
    bn_finalize<<<1, DD, 0, stream>>>(S1, S2, g2, be2, SC, SH, 1.0f / NN);
    bn_apply<<<bna_grid, 256, 0, stream>>>(CB, b2, SC, SH, CB, NN * DD);

    // ================= final: out = (h1 + h2) @ Wf + bf =================
    gemm_kernel<DD, DF, 64, 128, true, true>
        <<<(NN + 63) / 64, 128, 0, stream>>>(H1, CB, Wf, bf, out, NN);
}